// Round 3
// baseline (497.308 us; speedup 1.0000x reference)
//
#include <hip/hip_runtime.h>
#include <hip/hip_bf16.h>

typedef __attribute__((ext_vector_type(8))) short short8;
typedef __attribute__((ext_vector_type(4))) float floatx4;

#define N_ROWS   16384
#define IN_DIM   512
#define OUT_DIM  512
#define K_SPLINE 4096
#define K_TOT    4608
#define BM       64
#define BN       256
#define BK       64
#define NKT      (K_TOT / BK)    /* 72 */
#define NKTILE   (K_TOT / 32)    /* 144 */
#define L2E      1.4426950408889634f
#define C2E      0.13533528323661270f   /* exp(-2) */

__device__ __forceinline__ unsigned short f2bf(float f) {
    unsigned int u = __float_as_uint(f);
    unsigned int r = u + 0x7FFFu + ((u >> 16) & 1u);
    return (unsigned short)(r >> 16);
}

// pack two fp32 -> two bf16 (round-half-up) in one dword via v_perm_b32
__device__ __forceinline__ unsigned pack2bf(float f0, float f1) {
    unsigned u0 = __float_as_uint(f0) + 0x8000u;
    unsigned u1 = __float_as_uint(f1) + 0x8000u;
    return __builtin_amdgcn_perm(u1, u0, 0x07060302);
}

// ---------------------------------------------------------------------------
// prep v2: write B in MFMA B-fragment-tiled layout.
// Btf frag index = (ct*NKTILE + ktile)*64 + lane ; each frag elem j (0..7):
//   n = ct*16 + (lane&15), k = ktile*32 + (lane>>4)*8 + j
//   B[n][k] = k<4096 ? spline_weight[k][n] : base_w[n][k-4096]
// grid (NKTILE/4, OUT_DIM/16) = (36, 32), 256 threads.
// ---------------------------------------------------------------------------
__global__ __launch_bounds__(256) void prep_kernel(
    const float* __restrict__ sw, const float* __restrict__ bw,
    unsigned short* __restrict__ Btf)
{
    const int t     = threadIdx.x;
    const int lane  = t & 63;
    const int ktile = blockIdx.x * 4 + (t >> 6);
    const int ct    = blockIdx.y;
    const int mn    = lane & 15, q = lane >> 4;
    const int n     = ct * 16 + mn;
    const int kbase = ktile * 32 + q * 8;
    short8 v;
    if (kbase < K_SPLINE) {
        #pragma unroll
        for (int j = 0; j < 8; ++j)
            v[j] = (short)f2bf(sw[(size_t)(kbase + j) * OUT_DIM + n]);
    } else {
        #pragma unroll
        for (int j = 0; j < 8; ++j)
            v[j] = (short)f2bf(bw[(size_t)n * IN_DIM + (kbase + j - K_SPLINE)]);
    }
    reinterpret_cast<short8*>(Btf)[(size_t)(ct * NKTILE + ktile) * 64 + lane] = v;
}

// ---------------------------------------------------------------------------
// A staging into swizzled LDS buffer (64 rows x 64 bf16, 16B blocks ^ (row&7)).
// ---------------------------------------------------------------------------
__device__ __forceinline__ void stageA(unsigned short* dst, const float* xrow,
                                       int rowA, int colq, int kt)
{
    unsigned short* arow = dst + rowA * 64;
    if (kt < K_SPLINE / BK) {
        const float2 xv = *reinterpret_cast<const float2*>(xrow + kt * 8 + colq * 2);
        #pragma unroll
        for (int e = 0; e < 2; ++e) {
            const float X = e ? xv.y : xv.x;
            const float u = fmaf(1.75f, X, 3.5f);
            float b = __builtin_amdgcn_exp2f(-(u * u) * L2E);            // exp(-u^2)
            float r = __builtin_amdgcn_exp2f(fmaf(2.0f * L2E, u, -L2E)); // exp(2u-1)
            float v[8];
            v[0] = b;
            #pragma unroll
            for (int j = 1; j < 8; ++j) { b *= r; r *= C2E; v[j] = b; }
            uint4 p;
            p.x = pack2bf(v[0], v[1]);
            p.y = pack2bf(v[2], v[3]);
            p.z = pack2bf(v[4], v[5]);
            p.w = pack2bf(v[6], v[7]);
            const int blk = (colq * 2 + e) ^ (rowA & 7);
            *reinterpret_cast<uint4*>(arow + blk * 8) = p;
        }
    } else {
        const float* xs = xrow + (kt - K_SPLINE / BK) * 64 + colq * 16;
        const float4 a0 = *reinterpret_cast<const float4*>(xs);
        const float4 a1 = *reinterpret_cast<const float4*>(xs + 4);
        const float4 a2 = *reinterpret_cast<const float4*>(xs + 8);
        const float4 a3 = *reinterpret_cast<const float4*>(xs + 12);
        const float f[16] = {a0.x, a0.y, a0.z, a0.w, a1.x, a1.y, a1.z, a1.w,
                             a2.x, a2.y, a2.z, a2.w, a3.x, a3.y, a3.z, a3.w};
        float s[16];
        #pragma unroll
        for (int j = 0; j < 16; ++j)
            s[j] = f[j] * __builtin_amdgcn_rcpf(
                1.0f + __builtin_amdgcn_exp2f(-f[j] * L2E));
        #pragma unroll
        for (int e = 0; e < 2; ++e) {
            uint4 p;
            p.x = pack2bf(s[e * 8 + 0], s[e * 8 + 1]);
            p.y = pack2bf(s[e * 8 + 2], s[e * 8 + 3]);
            p.z = pack2bf(s[e * 8 + 4], s[e * 8 + 5]);
            p.w = pack2bf(s[e * 8 + 6], s[e * 8 + 7]);
            const int blk = (colq * 2 + e) ^ (rowA & 7);
            *reinterpret_cast<uint4*>(arow + blk * 8) = p;
        }
    }
}

// B fragment load: direct global -> registers (MFMA B layout, coalesced 16B/lane)
template<bool PREP>
__device__ __forceinline__ void load_bfrags(short8 dst[4][2], const short8* __restrict__ Bf,
                                            const size_t* bbase, int kt,
                                            const float* __restrict__ sw,
                                            const float* __restrict__ bw,
                                            int col0, int wn, int lane)
{
    if (PREP) {
        #pragma unroll
        for (int nt = 0; nt < 4; ++nt)
            #pragma unroll
            for (int s = 0; s < 2; ++s)
                dst[nt][s] = Bf[bbase[nt] + (size_t)(kt * 2 + s) * 64];
    } else {
        const int mn = lane & 15, q = lane >> 4;
        #pragma unroll
        for (int nt = 0; nt < 4; ++nt) {
            const int n = col0 + wn * 64 + nt * 16 + mn;
            #pragma unroll
            for (int s = 0; s < 2; ++s) {
                short8 v;
                #pragma unroll
                for (int j = 0; j < 8; ++j) {
                    const int k = (kt * 2 + s) * 32 + q * 8 + j;
                    const float val = (k < K_SPLINE)
                        ? sw[(size_t)k * OUT_DIM + n]
                        : bw[(size_t)n * IN_DIM + (k - K_SPLINE)];
                    v[j] = (short)f2bf(val);
                }
                dst[nt][s] = v;
            }
        }
    }
}

// ---------------------------------------------------------------------------
// Fused KAN main kernel.
//   BM=64, BN=256, 256 threads (4 waves), wave tile 64x64 (acc[4][4]).
//   A: generated on the fly -> LDS double buffer (one barrier/iter).
//   B: direct global->register fragments, 1-iter register prefetch.
// ---------------------------------------------------------------------------
template<bool PREP>
__global__ __launch_bounds__(256, 2) void kan_kernel(
    const float* __restrict__ x,
    const unsigned short* __restrict__ Btf,
    const float* __restrict__ sw,
    const float* __restrict__ bw,
    const float* __restrict__ bias,
    float* __restrict__ out)
{
    __shared__ unsigned short Als[2][BM * BK];   // 2 x 8 KB

    const int tid  = threadIdx.x;
    const int wn   = tid >> 6;          // wave 0..3 -> 64-col group
    const int lane = tid & 63;
    const int q    = lane >> 4;
    const int mn   = lane & 15;
    const int row0 = blockIdx.x * BM;
    const int col0 = blockIdx.y * BN;
    const int rowA = tid >> 2;          // 0..63
    const int colq = tid & 3;

    const float* xrow = x + (size_t)(row0 + rowA) * IN_DIM;

    size_t bbase[4];
    #pragma unroll
    for (int nt = 0; nt < 4; ++nt)
        bbase[nt] = (size_t)(((col0 >> 4) + wn * 4 + nt) * NKTILE) * 64 + lane;
    const short8* Bf = reinterpret_cast<const short8*>(Btf);

    floatx4 acc[4][4];
    #pragma unroll
    for (int i = 0; i < 4; ++i)
        #pragma unroll
        for (int j = 0; j < 4; ++j)
            acc[i][j] = (floatx4){0.f, 0.f, 0.f, 0.f};

    short8 bb[2][4][2];

    // prologue: stage iter 0
    stageA(&Als[0][0], xrow, rowA, colq, 0);
    load_bfrags<PREP>(bb[0], Bf, bbase, 0, sw, bw, col0, wn, lane);
    __syncthreads();

    for (int kt = 0; kt < NKT; ++kt) {
        const int cur = kt & 1;
        const int nxt = cur ^ 1;
        if (kt + 1 < NKT) {
            load_bfrags<PREP>(bb[nxt], Bf, bbase, kt + 1, sw, bw, col0, wn, lane);
            stageA(&Als[nxt][0], xrow, rowA, colq, kt + 1);
        }
        #pragma unroll
        for (int s = 0; s < 2; ++s) {
            short8 af[4];
            #pragma unroll
            for (int mt = 0; mt < 4; ++mt) {
                const int r = mt * 16 + mn;
                af[mt] = *reinterpret_cast<const short8*>(
                    &Als[cur][r * 64 + (((s * 4 + q) ^ (r & 7)) * 8)]);
            }
            #pragma unroll
            for (int mt = 0; mt < 4; ++mt)
                #pragma unroll
                for (int nt = 0; nt < 4; ++nt)
                    acc[mt][nt] = __builtin_amdgcn_mfma_f32_16x16x32_bf16(
                        af[mt], bb[cur][nt][s], acc[mt][nt], 0, 0, 0);
        }
        __syncthreads();
    }

    // epilogue: + bias, store fp32
    #pragma unroll
    for (int nt = 0; nt < 4; ++nt) {
        const int col = col0 + wn * 64 + nt * 16 + mn;
        const float bv = bias[col];
        #pragma unroll
        for (int mt = 0; mt < 4; ++mt) {
            const int rb = row0 + mt * 16 + q * 4;
            #pragma unroll
            for (int e = 0; e < 4; ++e)
                out[(size_t)(rb + e) * OUT_DIM + col] = acc[mt][nt][e] + bv;
        }
    }
}

extern "C" void kernel_launch(void* const* d_in, const int* in_sizes, int n_in,
                              void* d_out, int out_size, void* d_ws, size_t ws_size,
                              hipStream_t stream)
{
    const float* x    = (const float*)d_in[0];
    // d_in[1] = grid (linspace(-2,2,8)) — folded into constants
    const float* sw   = (const float*)d_in[2];
    const float* bw   = (const float*)d_in[3];
    const float* bias = (const float*)d_in[4];
    float* out = (float*)d_out;

    const size_t bt_bytes = (size_t)OUT_DIM * K_TOT * sizeof(unsigned short);
    if (ws_size >= bt_bytes) {
        unsigned short* Btf = (unsigned short*)d_ws;
        prep_kernel<<<dim3(NKTILE / 4, OUT_DIM / 16), 256, 0, stream>>>(sw, bw, Btf);
        kan_kernel<true><<<dim3(N_ROWS / BM, OUT_DIM / BN), 256, 0, stream>>>(
            x, Btf, sw, bw, bias, out);
    } else {
        kan_kernel<false><<<dim3(N_ROWS / BM, OUT_DIM / BN), 256, 0, stream>>>(
            x, nullptr, sw, bw, bias, out);
    }
}

// Round 4
// 174.388 us; speedup vs baseline: 2.8517x; 2.8517x over previous
//
#include <hip/hip_runtime.h>
#include <hip/hip_bf16.h>

typedef __attribute__((ext_vector_type(8))) short short8;
typedef __attribute__((ext_vector_type(4))) float floatx4;

#define N_ROWS   16384
#define IN_DIM   512
#define OUT_DIM  512
#define K_SPLINE 4096
#define K_TOT    4608
#define BM       64
#define BN       256
#define BK       64
#define NKT      (K_TOT / BK)    /* 72 */
#define NKTILE   (K_TOT / 32)    /* 144 */
#define L2E      1.4426950408889634f
#define C2E      0.13533528323661270f   /* exp(-2) */

__device__ __forceinline__ unsigned short f2bf(float f) {
    unsigned int u = __float_as_uint(f);
    unsigned int r = u + 0x7FFFu + ((u >> 16) & 1u);
    return (unsigned short)(r >> 16);
}

// pack two fp32 -> two bf16 (round-half-up) in one dword via v_perm_b32
__device__ __forceinline__ unsigned pack2bf(float f0, float f1) {
    unsigned u0 = __float_as_uint(f0) + 0x8000u;
    unsigned u1 = __float_as_uint(f1) + 0x8000u;
    return __builtin_amdgcn_perm(u1, u0, 0x07060302);
}

// ---------------------------------------------------------------------------
// prep: write B in MFMA B-fragment-tiled layout.
// Btf frag index = (ct*NKTILE + ktile)*64 + lane ; frag elem j (0..7):
//   n = ct*16 + (lane&15), k = ktile*32 + (lane>>4)*8 + j
//   B[n][k] = k<4096 ? spline_weight[k][n] : base_w[n][k-4096]
// ---------------------------------------------------------------------------
__global__ __launch_bounds__(256) void prep_kernel(
    const float* __restrict__ sw, const float* __restrict__ bw,
    unsigned short* __restrict__ Btf)
{
    const int t     = threadIdx.x;
    const int lane  = t & 63;
    const int ktile = blockIdx.x * 4 + (t >> 6);
    const int ct    = blockIdx.y;
    const int mn    = lane & 15, q = lane >> 4;
    const int n     = ct * 16 + mn;
    const int kbase = ktile * 32 + q * 8;
    short8 v;
    if (kbase < K_SPLINE) {
        #pragma unroll
        for (int j = 0; j < 8; ++j)
            v[j] = (short)f2bf(sw[(size_t)(kbase + j) * OUT_DIM + n]);
    } else {
        #pragma unroll
        for (int j = 0; j < 8; ++j)
            v[j] = (short)f2bf(bw[(size_t)n * IN_DIM + (kbase + j - K_SPLINE)]);
    }
    reinterpret_cast<short8*>(Btf)[(size_t)(ct * NKTILE + ktile) * 64 + lane] = v;
}

// ---------------------------------------------------------------------------
// A staging into swizzled LDS buffer (64 rows x 64 bf16, 16B blocks ^ (row&7)).
// ---------------------------------------------------------------------------
__device__ __forceinline__ void stageA(unsigned short* dst, const float* xrow,
                                       int rowA, int colq, int kt)
{
    unsigned short* arow = dst + rowA * 64;
    if (kt < K_SPLINE / BK) {
        const float2 xv = *reinterpret_cast<const float2*>(xrow + kt * 8 + colq * 2);
        #pragma unroll
        for (int e = 0; e < 2; ++e) {
            const float X = e ? xv.y : xv.x;
            const float u = fmaf(1.75f, X, 3.5f);
            float b = __builtin_amdgcn_exp2f(-(u * u) * L2E);            // exp(-u^2)
            float r = __builtin_amdgcn_exp2f(fmaf(2.0f * L2E, u, -L2E)); // exp(2u-1)
            float v[8];
            v[0] = b;
            #pragma unroll
            for (int j = 1; j < 8; ++j) { b *= r; r *= C2E; v[j] = b; }
            uint4 p;
            p.x = pack2bf(v[0], v[1]);
            p.y = pack2bf(v[2], v[3]);
            p.z = pack2bf(v[4], v[5]);
            p.w = pack2bf(v[6], v[7]);
            const int blk = (colq * 2 + e) ^ (rowA & 7);
            *reinterpret_cast<uint4*>(arow + blk * 8) = p;
        }
    } else {
        const float* xs = xrow + (kt - K_SPLINE / BK) * 64 + colq * 16;
        const float4 a0 = *reinterpret_cast<const float4*>(xs);
        const float4 a1 = *reinterpret_cast<const float4*>(xs + 4);
        const float4 a2 = *reinterpret_cast<const float4*>(xs + 8);
        const float4 a3 = *reinterpret_cast<const float4*>(xs + 12);
        const float f[16] = {a0.x, a0.y, a0.z, a0.w, a1.x, a1.y, a1.z, a1.w,
                             a2.x, a2.y, a2.z, a2.w, a3.x, a3.y, a3.z, a3.w};
        float s[16];
        #pragma unroll
        for (int j = 0; j < 16; ++j)
            s[j] = f[j] * __builtin_amdgcn_rcpf(
                1.0f + __builtin_amdgcn_exp2f(-f[j] * L2E));
        #pragma unroll
        for (int e = 0; e < 2; ++e) {
            uint4 p;
            p.x = pack2bf(s[e * 8 + 0], s[e * 8 + 1]);
            p.y = pack2bf(s[e * 8 + 2], s[e * 8 + 3]);
            p.z = pack2bf(s[e * 8 + 4], s[e * 8 + 5]);
            p.w = pack2bf(s[e * 8 + 6], s[e * 8 + 7]);
            const int blk = (colq * 2 + e) ^ (rowA & 7);
            *reinterpret_cast<uint4*>(arow + blk * 8) = p;
        }
    }
}

// B fragment load: direct global -> registers (MFMA B layout, coalesced 16B/lane)
template<bool PREP>
__device__ __forceinline__ void load_bfrags(short8 dst[4][2], const short8* __restrict__ Bf,
                                            const size_t* bbase, int kt,
                                            const float* __restrict__ sw,
                                            const float* __restrict__ bw,
                                            int col0, int wn, int lane)
{
    if (PREP) {
        #pragma unroll
        for (int nt = 0; nt < 4; ++nt)
            #pragma unroll
            for (int s = 0; s < 2; ++s)
                dst[nt][s] = Bf[bbase[nt] + (size_t)(kt * 2 + s) * 64];
    } else {
        const int mn = lane & 15, q = lane >> 4;
        #pragma unroll
        for (int nt = 0; nt < 4; ++nt) {
            const int n = col0 + wn * 64 + nt * 16 + mn;
            #pragma unroll
            for (int s = 0; s < 2; ++s) {
                short8 v;
                #pragma unroll
                for (int j = 0; j < 8; ++j) {
                    const int k = (kt * 2 + s) * 32 + q * 8 + j;
                    const float val = (k < K_SPLINE)
                        ? sw[(size_t)k * OUT_DIM + n]
                        : bw[(size_t)n * IN_DIM + (k - K_SPLINE)];
                    v[j] = (short)f2bf(val);
                }
                dst[nt][s] = v;
            }
        }
    }
}

// ---------------------------------------------------------------------------
// Fused KAN main kernel.
//   BM=64, BN=256, 256 threads (4 waves), wave tile 64x64 (acc[4][4]).
//   A: generated on the fly -> LDS double buffer (one barrier/iter).
//   B: direct global->register fragments, 1-iter register prefetch.
//   NOTE: double-buffer selectors are COMPILE-TIME (manual 2x unroll) —
//   runtime-indexed register arrays spill to scratch (R3: 1.19 GB writes).
// ---------------------------------------------------------------------------
template<bool PREP>
__global__ __launch_bounds__(256, 2) void kan_kernel(
    const float* __restrict__ x,
    const unsigned short* __restrict__ Btf,
    const float* __restrict__ sw,
    const float* __restrict__ bw,
    const float* __restrict__ bias,
    float* __restrict__ out)
{
    __shared__ unsigned short Als[2][BM * BK];   // 2 x 8 KB

    const int tid  = threadIdx.x;
    const int wn   = tid >> 6;          // wave 0..3 -> 64-col group
    const int lane = tid & 63;
    const int q    = lane >> 4;
    const int mn   = lane & 15;
    const int row0 = blockIdx.x * BM;
    const int col0 = blockIdx.y * BN;
    const int rowA = tid >> 2;          // 0..63
    const int colq = tid & 3;

    const float* xrow = x + (size_t)(row0 + rowA) * IN_DIM;

    size_t bbase[4];
    #pragma unroll
    for (int nt = 0; nt < 4; ++nt)
        bbase[nt] = (size_t)(((col0 >> 4) + wn * 4 + nt) * NKTILE) * 64 + lane;
    const short8* Bf = reinterpret_cast<const short8*>(Btf);

    floatx4 acc[4][4];
    #pragma unroll
    for (int i = 0; i < 4; ++i)
        #pragma unroll
        for (int j = 0; j < 4; ++j)
            acc[i][j] = (floatx4){0.f, 0.f, 0.f, 0.f};

    short8 bb[2][4][2];

    // prologue: stage iter 0 into buffer 0
    stageA(&Als[0][0], xrow, rowA, colq, 0);
    load_bfrags<PREP>(bb[0], Bf, bbase, 0, sw, bw, col0, wn, lane);
    __syncthreads();

    for (int ktb = 0; ktb < NKT; ktb += 2) {
        #pragma unroll
        for (int half = 0; half < 2; ++half) {       // cur/nxt are literals
            const int kt  = ktb + half;
            const int cur = half;
            const int nxt = half ^ 1;
            if (kt + 1 < NKT) {
                load_bfrags<PREP>(bb[nxt], Bf, bbase, kt + 1, sw, bw, col0, wn, lane);
                stageA(&Als[nxt][0], xrow, rowA, colq, kt + 1);
            }
            #pragma unroll
            for (int s = 0; s < 2; ++s) {
                short8 af[4];
                #pragma unroll
                for (int mt = 0; mt < 4; ++mt) {
                    const int r = mt * 16 + mn;
                    af[mt] = *reinterpret_cast<const short8*>(
                        &Als[cur][r * 64 + (((s * 4 + q) ^ (r & 7)) * 8)]);
                }
                #pragma unroll
                for (int mt = 0; mt < 4; ++mt)
                    #pragma unroll
                    for (int nt = 0; nt < 4; ++nt)
                        acc[mt][nt] = __builtin_amdgcn_mfma_f32_16x16x32_bf16(
                            af[mt], bb[cur][nt][s], acc[mt][nt], 0, 0, 0);
            }
            __syncthreads();
        }
    }

    // epilogue: + bias, store fp32
    #pragma unroll
    for (int nt = 0; nt < 4; ++nt) {
        const int col = col0 + wn * 64 + nt * 16 + mn;
        const float bv = bias[col];
        #pragma unroll
        for (int mt = 0; mt < 4; ++mt) {
            const int rb = row0 + mt * 16 + q * 4;
            #pragma unroll
            for (int e = 0; e < 4; ++e)
                out[(size_t)(rb + e) * OUT_DIM + col] = acc[mt][nt][e] + bv;
        }
    }
}

extern "C" void kernel_launch(void* const* d_in, const int* in_sizes, int n_in,
                              void* d_out, int out_size, void* d_ws, size_t ws_size,
                              hipStream_t stream)
{
    const float* x    = (const float*)d_in[0];
    // d_in[1] = grid (linspace(-2,2,8)) — folded into constants
    const float* sw   = (const float*)d_in[2];
    const float* bw   = (const float*)d_in[3];
    const float* bias = (const float*)d_in[4];
    float* out = (float*)d_out;

    const size_t bt_bytes = (size_t)OUT_DIM * K_TOT * sizeof(unsigned short);
    if (ws_size >= bt_bytes) {
        unsigned short* Btf = (unsigned short*)d_ws;
        prep_kernel<<<dim3(NKTILE / 4, OUT_DIM / 16), 256, 0, stream>>>(sw, bw, Btf);
        kan_kernel<true><<<dim3(N_ROWS / BM, OUT_DIM / BN), 256, 0, stream>>>(
            x, Btf, sw, bw, bias, out);
    } else {
        kan_kernel<false><<<dim3(N_ROWS / BM, OUT_DIM / BN), 256, 0, stream>>>(
            x, nullptr, sw, bw, bias, out);
    }
}